// Round 2
// baseline (857.192 us; speedup 1.0000x reference)
//
#include <hip/hip_runtime.h>
#include <math.h>

#define B_  4
#define S_  4096
#define D_  1024
#define HD_ 64

// ------------------------------------------------------------------
// Kernel 1: QKV projection.  q/k/v[b,s,h] = dot(x[b,s,:], w*[h,:]) + b*[h]
// 16 x-rows per block staged in LDS (two 32KB halves), 192 active threads
// each own one (proj, h) output column across all 16 rows.
// LDS reads are wave-uniform (broadcast, conflict-free).
// ------------------------------------------------------------------
#define PROJ_ROWS 16

__global__ __launch_bounds__(256) void proj_kernel(
    const float* __restrict__ x,
    const float* __restrict__ wq, const float* __restrict__ bq,
    const float* __restrict__ wk, const float* __restrict__ bk,
    const float* __restrict__ wv, const float* __restrict__ bv,
    float* __restrict__ qo, float* __restrict__ ko, float* __restrict__ vo)
{
    __shared__ float xs[PROJ_ROWS][512];   // 32 KB, one K-half at a time
    const int t = threadIdx.x;
    const size_t row0 = (size_t)blockIdx.x * PROJ_ROWS;

    const int p = t >> 6;          // 0=q 1=k 2=v (t<192)
    const int h = t & 63;
    const float* w = (p == 0 ? wq : (p == 1 ? wk : wv)) + (size_t)h * D_;
    const float4* w4 = (const float4*)w;

    float acc[PROJ_ROWS];
#pragma unroll
    for (int r = 0; r < PROJ_ROWS; ++r) acc[r] = 0.f;

    for (int half = 0; half < 2; ++half) {
        __syncthreads();
        // stage 16 rows x 512 floats = 2048 float4, 8 per thread, coalesced
        float4* xs4 = (float4*)&xs[0][0];
#pragma unroll
        for (int i = 0; i < 8; ++i) {
            int e = t + i * 256;          // 0..2047
            int r = e >> 7;               // 128 float4 per row-half
            int c = e & 127;
            xs4[e] = *(const float4*)&x[(row0 + r) * D_ + half * 512 + c * 4];
        }
        __syncthreads();

        if (t < 192) {
            for (int kk = 0; kk < 128; ++kk) {
                const float4 wv4 = w4[half * 128 + kk];
#pragma unroll
                for (int r = 0; r < PROJ_ROWS; ++r) {
                    const float4 xv = *(const float4*)&xs[r][kk * 4];
                    acc[r] += wv4.x * xv.x + wv4.y * xv.y + wv4.z * xv.z + wv4.w * xv.w;
                }
            }
        }
    }

    if (t < 192) {
        const float bias = (p == 0 ? bq : (p == 1 ? bk : bv))[h];
        float* out = (p == 0 ? qo : (p == 1 ? ko : vo));
#pragma unroll
        for (int r = 0; r < PROJ_ROWS; ++r)
            out[(row0 + r) * HD_ + h] = acc[r] + bias;
    }
}

// ------------------------------------------------------------------
// Kernel 2: causal flash attention, fp32.
// Block = 256 threads, handles one (batch, 64-query tile).
// Thread (qr = t>>2, tc = t&3): scores for kc = tc+4i, output dims
// h = tc*16 .. +15.  m/l replicated per quad in registers; P stays in
// registers and is shuffled to quad-mates during PV accumulation.
// ------------------------------------------------------------------
#define TQ 64
#define TK 64
#define KPAD (HD_ + 4)   // 68 floats: 272B row stride, 16B aligned, bank-skewed

__global__ __launch_bounds__(256) void flash_kernel(
    const float* __restrict__ qg, const float* __restrict__ kg,
    const float* __restrict__ vg, float* __restrict__ out)
{
    __shared__ float qT[HD_][TQ];     // qT[h][r]  (16 KB)
    __shared__ float ks[TK][KPAD];    // 17 KB
    __shared__ float vs[TK][KPAD];    // 17 KB

    const int t    = threadIdx.x;
    const int lane = t & 63;
    const int qr   = t >> 2;     // 0..63 query row in tile
    const int tc   = t & 3;
    const int hb   = tc * 16;    // output dim base
    const int qi   = blockIdx.x; // q tile index
    const int b    = blockIdx.y;

    const size_t qbase = ((size_t)b * S_ + (size_t)qi * TQ) * HD_;

    // stage Q transposed (once). Bank-conflicted writes but tiny vs total work.
#pragma unroll
    for (int i = 0; i < 16; ++i) {
        int e = t + i * 256;     // 0..4095
        int r = e >> 6, hh = e & 63;
        qT[hh][r] = qg[qbase + e];
    }

    float o[16];
#pragma unroll
    for (int j = 0; j < 16; ++j) o[j] = 0.f;
    float m_r = -INFINITY, l_r = 0.f;

    for (int kt = 0; kt <= qi; ++kt) {
        __syncthreads();   // protect ks/vs (and qT on first iter)
        const float4* kg4 = (const float4*)(kg + ((size_t)b * S_ + (size_t)kt * TK) * HD_);
        const float4* vg4 = (const float4*)(vg + ((size_t)b * S_ + (size_t)kt * TK) * HD_);
#pragma unroll
        for (int i = 0; i < 4; ++i) {
            int e = t + i * 256;            // 0..1023 float4
            int r = e >> 4, c = (e & 15) * 4;
            *(float4*)&ks[r][c] = kg4[e];
            *(float4*)&vs[r][c] = vg4[e];
        }
        __syncthreads();

        // ---- scores: s[i] = q[qr,:] . k[tc+4i,:] ----
        float s[16];
#pragma unroll
        for (int i = 0; i < 16; ++i) s[i] = 0.f;
        for (int hh = 0; hh < HD_; hh += 4) {
            const float q0 = qT[hh][qr], q1 = qT[hh + 1][qr];
            const float q2 = qT[hh + 2][qr], q3 = qT[hh + 3][qr];
#pragma unroll
            for (int i = 0; i < 16; ++i) {
                const float4 kv = *(const float4*)&ks[tc + 4 * i][hh];
                s[i] += q0 * kv.x + q1 * kv.y + q2 * kv.z + q3 * kv.w;
            }
        }

        const bool diag = (kt == qi);
        float mx = -INFINITY;
#pragma unroll
        for (int i = 0; i < 16; ++i) {
            s[i] *= 0.125f;                       // 1/sqrt(64)
            if (diag && (tc + 4 * i > qr)) s[i] = -INFINITY;
            mx = fmaxf(mx, s[i]);
        }
        mx = fmaxf(mx, __shfl_xor(mx, 1));
        mx = fmaxf(mx, __shfl_xor(mx, 2));        // quad = row max

        const float m_new = fmaxf(m_r, mx);
        const float alpha = __expf(m_r - m_new);  // exp(-inf)=0 on first tile
        float p[16], psum = 0.f;
#pragma unroll
        for (int i = 0; i < 16; ++i) {
            p[i] = __expf(s[i] - m_new);
            psum += p[i];
        }
        psum += __shfl_xor(psum, 1);
        psum += __shfl_xor(psum, 2);
        l_r = l_r * alpha + psum;
        m_r = m_new;

#pragma unroll
        for (int j = 0; j < 16; ++j) o[j] *= alpha;

        // ---- PV: o[qr][hb..hb+15] += sum_kc p[qr][kc] * v[kc][:] ----
        const int base = lane & ~3;
#pragma unroll
        for (int i = 0; i < 16; ++i) {
#pragma unroll
            for (int c = 0; c < 4; ++c) {
                const int kc = 4 * i + c;                 // lane base+c holds it in p[i]
                const float pv = __shfl(p[i], base + c);
                const float4 v0 = *(const float4*)&vs[kc][hb];
                const float4 v1 = *(const float4*)&vs[kc][hb + 4];
                const float4 v2 = *(const float4*)&vs[kc][hb + 8];
                const float4 v3 = *(const float4*)&vs[kc][hb + 12];
                o[0]  += pv * v0.x; o[1]  += pv * v0.y; o[2]  += pv * v0.z; o[3]  += pv * v0.w;
                o[4]  += pv * v1.x; o[5]  += pv * v1.y; o[6]  += pv * v1.z; o[7]  += pv * v1.w;
                o[8]  += pv * v2.x; o[9]  += pv * v2.y; o[10] += pv * v2.z; o[11] += pv * v2.w;
                o[12] += pv * v3.x; o[13] += pv * v3.y; o[14] += pv * v3.z; o[15] += pv * v3.w;
            }
        }
    }

    const float inv = 1.f / l_r;
    float* op = out + qbase + (size_t)qr * HD_ + hb;
#pragma unroll
    for (int w = 0; w < 4; ++w) {
        float4 r;
        r.x = o[4 * w + 0] * inv; r.y = o[4 * w + 1] * inv;
        r.z = o[4 * w + 2] * inv; r.w = o[4 * w + 3] * inv;
        *(float4*)&op[4 * w] = r;
    }
}

// ------------------------------------------------------------------
extern "C" void kernel_launch(void* const* d_in, const int* in_sizes, int n_in,
                              void* d_out, int out_size, void* d_ws, size_t ws_size,
                              hipStream_t stream)
{
    const float* x  = (const float*)d_in[0];
    const float* wq = (const float*)d_in[1];
    const float* bq = (const float*)d_in[2];
    const float* wk = (const float*)d_in[3];
    const float* bk = (const float*)d_in[4];
    const float* wv = (const float*)d_in[5];
    const float* bv = (const float*)d_in[6];
    float* outp = (float*)d_out;

    // workspace: q,k,v fp32 [B,S,HD] = 3 * 4 MiB = 12 MiB
    const size_t n = (size_t)B_ * S_ * HD_;
    float* qb = (float*)d_ws;
    float* kb = qb + n;
    float* vb = kb + n;

    proj_kernel<<<dim3(B_ * S_ / PROJ_ROWS), 256, 0, stream>>>(
        x, wq, bq, wk, bk, wv, bv, qb, kb, vb);
    flash_kernel<<<dim3(S_ / TQ, B_), 256, 0, stream>>>(qb, kb, vb, outp);
}

// Round 3
// 394.304 us; speedup vs baseline: 2.1739x; 2.1739x over previous
//
#include <hip/hip_runtime.h>
#include <math.h>

#define B_   4
#define S_   4096
#define D_   1024
#define HD_  64

// ---------------- split-K flash constants ----------------
#define CK            8          // k-tiles (of 64 keys) per chunk
#define CHUNKS_PER_B  288        // sum_{qi=0}^{63} (qi/8 + 1)
#define PSTRIDE       68         // floats per row in a partial slot (o[64], m, l, pad)
#define SLOT_F        (64 * PSTRIDE)

typedef float  f32x4  __attribute__((ext_vector_type(4)));
typedef __bf16 bf16x8 __attribute__((ext_vector_type(8)));

static __device__ __forceinline__ unsigned short f2bf(float f) {
    unsigned int u = __float_as_uint(f);
    u += 0x7FFFu + ((u >> 16) & 1u);          // round-to-nearest-even
    return (unsigned short)(u >> 16);
}

// ------------------------------------------------------------------
// Kernel 0: convert wq/wk/wv (fp32 [64][1024]) into wbf (bf16 [192][1024]).
// col = p*64 + h. One block per col, 256 threads x 1 float4 each.
// ------------------------------------------------------------------
__global__ __launch_bounds__(256) void convert_w(
    const float* __restrict__ wq, const float* __restrict__ wk,
    const float* __restrict__ wv, unsigned short* __restrict__ wbf)
{
    const int col = blockIdx.x;            // 0..191
    const int p = col >> 6, h = col & 63;
    const float* src = (p == 0 ? wq : (p == 1 ? wk : wv)) + (size_t)h * D_;
    const int t = threadIdx.x;
    const float4 v = ((const float4*)src)[t];
    ushort4 o;
    o.x = f2bf(v.x); o.y = f2bf(v.y); o.z = f2bf(v.z); o.w = f2bf(v.w);
    *(ushort4*)&wbf[(size_t)col * D_ + 4 * t] = o;
}

// ------------------------------------------------------------------
// Kernel 1: QKV projection via bf16 MFMA (16x16x32).
// Block = 256 thr = 4 waves, computes 64 rows x 192 cols.
// Wave w owns rows 16w..16w+15; each wave does all 12 col-tiles.
// K staged in 64-wide chunks: x converted fp32->bf16 into LDS,
// w copied bf16 global -> LDS. Fragment layouts (m89-verified):
//   A: lane elem j = A[m = lane&15][k = (lane>>4)*8 + j]
//   B: lane elem j = B[k = (lane>>4)*8 + j][n = lane&15] = w[n][k]
//   C/D: reg r -> row = (lane>>4)*4 + r, col = lane&15
// ------------------------------------------------------------------
__global__ __launch_bounds__(256) void proj_mfma(
    const float* __restrict__ x, const unsigned short* __restrict__ wbf,
    const float* __restrict__ bq, const float* __restrict__ bk,
    const float* __restrict__ bv,
    float* __restrict__ qo, float* __restrict__ ko, float* __restrict__ vo)
{
    __shared__ unsigned short xbf[64][72];    // 9216 B  (stride 144B = 9x16B, odd)
    __shared__ unsigned short wsh[192][72];   // 27648 B

    const int t = threadIdx.x;
    const int wid = t >> 6, lane = t & 63;
    const size_t row0 = (size_t)blockIdx.x * 64;

    f32x4 acc[12];
#pragma unroll
    for (int i = 0; i < 12; ++i) acc[i] = (f32x4)0.f;

    const int arow = 16 * wid + (lane & 15);
    const int koff = (lane >> 4) * 8;

    for (int chunk = 0; chunk < 16; ++chunk) {
        const int d0 = chunk * 64;
        __syncthreads();
        // stage x: 64 rows x 64 d, fp32 -> bf16
#pragma unroll
        for (int i = 0; i < 4; ++i) {
            int e = t + i * 256;              // 0..1023 float4
            int r = e >> 4, c4 = e & 15;
            float4 v = *(const float4*)&x[(row0 + r) * D_ + d0 + 4 * c4];
            ushort4 o;
            o.x = f2bf(v.x); o.y = f2bf(v.y); o.z = f2bf(v.z); o.w = f2bf(v.w);
            *(ushort4*)&xbf[r][4 * c4] = o;
        }
        // stage w: 192 cols x 64 d bf16 (16B per thread-iter)
#pragma unroll
        for (int i = 0; i < 6; ++i) {
            int e = t + i * 256;              // 0..1535
            int col = e >> 3, g = e & 7;
            uint4 v = *(const uint4*)&wbf[(size_t)col * D_ + d0 + 8 * g];
            *(uint4*)&wsh[col][8 * g] = v;
        }
        __syncthreads();

#pragma unroll
        for (int ks2 = 0; ks2 < 2; ++ks2) {
            const int k0 = ks2 * 32;
            const bf16x8 a = *(const bf16x8*)&xbf[arow][k0 + koff];
#pragma unroll
            for (int ct = 0; ct < 12; ++ct) {
                const bf16x8 b = *(const bf16x8*)&wsh[16 * ct + (lane & 15)][k0 + koff];
                acc[ct] = __builtin_amdgcn_mfma_f32_16x16x32_bf16(a, b, acc[ct], 0, 0, 0);
            }
        }
    }

    // epilogue: add bias, scatter to q/k/v
#pragma unroll
    for (int ct = 0; ct < 12; ++ct) {
        const int p = ct >> 2, h0 = (ct & 3) * 16;
        const float* bias = (p == 0 ? bq : (p == 1 ? bk : bv));
        float* out = (p == 0 ? qo : (p == 1 ? ko : vo));
        const float bb = bias[h0 + (lane & 15)];
#pragma unroll
        for (int r = 0; r < 4; ++r) {
            const int row = 16 * wid + (lane >> 4) * 4 + r;
            out[(row0 + row) * HD_ + h0 + (lane & 15)] = acc[ct][r] + bb;
        }
    }
}

// ------------------------------------------------------------------
// Kernel 2: split-K causal flash attention (fp32 math).
// Block = 256 thr: thread (qr = t>>2, tc = t&3). Q in registers
// (quad-split over dims), scores quad-reduced, online softmax per
// 16-key group (scores replicated in quad -> no cross-lane max/P-shfl).
// Chunk = up to CK k-tiles. nc==1 writes out directly, else partials.
// ------------------------------------------------------------------
__global__ __launch_bounds__(256) void flash_splitk(
    const float* __restrict__ qg, const float* __restrict__ kg,
    const float* __restrict__ vg, float* __restrict__ out,
    float* __restrict__ part)
{
    __shared__ float ks[64][64];   // 16 KB
    __shared__ float vs[64][64];   // 16 KB

    const int t  = threadIdx.x;
    const int qr = t >> 2, tc = t & 3;
    const int b  = blockIdx.y;

    // decode blockIdx.x -> (qi, c); slot index within batch == blockIdx.x
    int qi = 0, rem = blockIdx.x;
    while (rem >= ((qi >> 3) + 1)) { rem -= (qi >> 3) + 1; ++qi; }
    const int c  = rem;
    const int nc = (qi >> 3) + 1;
    const int kt0 = c * CK;
    const int kt1 = min(qi, kt0 + CK - 1);

    const size_t qbase = ((size_t)b * S_ + (size_t)qi * 64) * HD_;

    // Q into registers, pre-scaled by 1/sqrt(64); per-thread offset = 16*t
    float4 ql[4];
#pragma unroll
    for (int j = 0; j < 4; ++j) {
        float4 v = *(const float4*)&qg[qbase + 16 * t + 4 * j];
        v.x *= 0.125f; v.y *= 0.125f; v.z *= 0.125f; v.w *= 0.125f;
        ql[j] = v;
    }

    float o[16];
#pragma unroll
    for (int j = 0; j < 16; ++j) o[j] = 0.f;
    float m_r = -INFINITY, l_r = 0.f;

    for (int kt = kt0; kt <= kt1; ++kt) {
        __syncthreads();
        const float4* kg4 = (const float4*)(kg + ((size_t)b * S_ + (size_t)kt * 64) * HD_);
        const float4* vg4 = (const float4*)(vg + ((size_t)b * S_ + (size_t)kt * 64) * HD_);
#pragma unroll
        for (int i = 0; i < 4; ++i) {
            int e = t + i * 256;               // 0..1023 float4
            int r = e >> 4, cc = (e & 15) * 4;
            *(float4*)&ks[r][cc] = kg4[e];
            *(float4*)&vs[r][cc] = vg4[e];
        }
        __syncthreads();

        const bool diag = (kt == qi);
        for (int grp = 0; grp < 4; ++grp) {
            if (diag && (grp << 4) > qr) break;   // fully-masked groups (ascending)

            float s[16];
#pragma unroll
            for (int i = 0; i < 16; ++i) {
                const int kc = (grp << 4) + i;
                const float4* kr = (const float4*)&ks[kc][tc * 16];
                float ss = 0.f;
#pragma unroll
                for (int j = 0; j < 4; ++j) {
                    const float4 kv = kr[j];
                    ss += ql[j].x * kv.x + ql[j].y * kv.y + ql[j].z * kv.z + ql[j].w * kv.w;
                }
                ss += __shfl_xor(ss, 1);
                ss += __shfl_xor(ss, 2);          // full 64-dim score, replicated in quad
                if (diag && kc > qr) ss = -INFINITY;
                s[i] = ss;
            }

            float mx = s[0];
#pragma unroll
            for (int i = 1; i < 16; ++i) mx = fmaxf(mx, s[i]);
            const float m_new = fmaxf(m_r, mx);
            const float alpha = __expf(m_r - m_new);
            float psum = 0.f;
#pragma unroll
            for (int i = 0; i < 16; ++i) {
                s[i] = __expf(s[i] - m_new);
                psum += s[i];
            }
            l_r = l_r * alpha + psum;
            m_r = m_new;
#pragma unroll
            for (int j = 0; j < 16; ++j) o[j] *= alpha;

#pragma unroll
            for (int i = 0; i < 16; ++i) {
                const int kc = (grp << 4) + i;
                const float pv = s[i];
                const float4* vr = (const float4*)&vs[kc][tc * 16];
#pragma unroll
                for (int j = 0; j < 4; ++j) {
                    const float4 vv = vr[j];
                    o[4 * j + 0] += pv * vv.x; o[4 * j + 1] += pv * vv.y;
                    o[4 * j + 2] += pv * vv.z; o[4 * j + 3] += pv * vv.w;
                }
            }
        }
    }

    if (nc == 1) {
        const float inv = 1.f / l_r;
#pragma unroll
        for (int j = 0; j < 4; ++j) {
            float4 r;
            r.x = o[4 * j + 0] * inv; r.y = o[4 * j + 1] * inv;
            r.z = o[4 * j + 2] * inv; r.w = o[4 * j + 3] * inv;
            *(float4*)&out[qbase + 16 * t + 4 * j] = r;
        }
    } else {
        const size_t sb = ((size_t)b * CHUNKS_PER_B + blockIdx.x) * SLOT_F;
#pragma unroll
        for (int j = 0; j < 4; ++j) {
            float4 r;
            r.x = o[4 * j + 0]; r.y = o[4 * j + 1];
            r.z = o[4 * j + 2]; r.w = o[4 * j + 3];
            *(float4*)&part[sb + qr * PSTRIDE + tc * 16 + 4 * j] = r;
        }
        if (tc == 0) {
            part[sb + qr * PSTRIDE + 64] = m_r;
            part[sb + qr * PSTRIDE + 65] = l_r;
        }
    }
}

// ------------------------------------------------------------------
// Kernel 3: merge partials for qi >= CK.  grid = (56, B).
// ------------------------------------------------------------------
__global__ __launch_bounds__(256) void combine(
    const float* __restrict__ part, float* __restrict__ out)
{
    const int t  = threadIdx.x;
    const int qr = t >> 2, tc = t & 3;
    const int qi = blockIdx.x + CK;          // 8..63
    const int b  = blockIdx.y;
    const int nc = (qi >> 3) + 1;

    int cum = 0;
    for (int j = 0; j < qi; ++j) cum += (j >> 3) + 1;
    const size_t base0 = ((size_t)b * CHUNKS_PER_B + cum) * SLOT_F;

    float M = -INFINITY;
    for (int c0 = 0; c0 < nc; ++c0)
        M = fmaxf(M, part[base0 + (size_t)c0 * SLOT_F + qr * PSTRIDE + 64]);

    float L = 0.f;
    float o[16];
#pragma unroll
    for (int j = 0; j < 16; ++j) o[j] = 0.f;

    for (int c0 = 0; c0 < nc; ++c0) {
        const size_t sb = base0 + (size_t)c0 * SLOT_F + qr * PSTRIDE;
        const float m_c = part[sb + 64];
        const float l_c = part[sb + 65];
        const float w = __expf(m_c - M);
        L += w * l_c;
#pragma unroll
        for (int j = 0; j < 4; ++j) {
            const float4 ov = *(const float4*)&part[sb + tc * 16 + 4 * j];
            o[4 * j + 0] += w * ov.x; o[4 * j + 1] += w * ov.y;
            o[4 * j + 2] += w * ov.z; o[4 * j + 3] += w * ov.w;
        }
    }

    const float inv = 1.f / L;
    const size_t qbase = ((size_t)b * S_ + (size_t)qi * 64) * HD_;
#pragma unroll
    for (int j = 0; j < 4; ++j) {
        float4 r;
        r.x = o[4 * j + 0] * inv; r.y = o[4 * j + 1] * inv;
        r.z = o[4 * j + 2] * inv; r.w = o[4 * j + 3] * inv;
        *(float4*)&out[qbase + 16 * t + 4 * j] = r;
    }
}

// ------------------------------------------------------------------
extern "C" void kernel_launch(void* const* d_in, const int* in_sizes, int n_in,
                              void* d_out, int out_size, void* d_ws, size_t ws_size,
                              hipStream_t stream)
{
    const float* x  = (const float*)d_in[0];
    const float* wq = (const float*)d_in[1];
    const float* bq = (const float*)d_in[2];
    const float* wk = (const float*)d_in[3];
    const float* bk = (const float*)d_in[4];
    const float* wv = (const float*)d_in[5];
    const float* bv = (const float*)d_in[6];
    float* outp = (float*)d_out;

    // ws layout (floats): q | k | v | wbf(bf16, 98304 float-equiv) | partials
    const size_t n = (size_t)B_ * S_ * HD_;        // 1048576
    float* qb = (float*)d_ws;
    float* kb = qb + n;
    float* vb = kb + n;
    unsigned short* wbf = (unsigned short*)(vb + n);          // 192*1024 bf16
    float* part = (float*)(wbf + (size_t)192 * D_);           // 4*288*4352 floats

    convert_w<<<dim3(192), 256, 0, stream>>>(wq, wk, wv, wbf);
    proj_mfma<<<dim3(B_ * S_ / 64), 256, 0, stream>>>(
        x, wbf, bq, bk, bv, qb, kb, vb);
    flash_splitk<<<dim3(CHUNKS_PER_B, B_), 256, 0, stream>>>(qb, kb, vb, outp, part);
    combine<<<dim3(S_ / 64 - CK, B_), 256, 0, stream>>>(part, outp);
}

// Round 4
// 194.685 us; speedup vs baseline: 4.4030x; 2.0253x over previous
//
#include <hip/hip_runtime.h>
#include <math.h>

#define B_   4
#define S_   4096
#define D_   1024
#define HD_  64

// ---------------- split-K flash constants ----------------
#define CK            8          // k-tiles (of 64 keys) per chunk
#define CHUNKS_PER_B  288        // sum_{qi=0}^{63} (qi/8 + 1)
#define PSTRIDE       68         // floats per row in a partial slot (o[64], m, l, pad)
#define SLOT_F        (64 * PSTRIDE)

typedef float  f32x4  __attribute__((ext_vector_type(4)));
typedef __bf16 bf16x8 __attribute__((ext_vector_type(8)));

static __device__ __forceinline__ unsigned short f2bf(float f) {
    unsigned int u = __float_as_uint(f);
    u += 0x7FFFu + ((u >> 16) & 1u);          // round-to-nearest-even
    return (unsigned short)(u >> 16);
}

// ------------------------------------------------------------------
// Kernel 0: convert wq/wk/wv (fp32 [64][1024]) into wbf (bf16 [192][1024]).
// ------------------------------------------------------------------
__global__ __launch_bounds__(256) void convert_w(
    const float* __restrict__ wq, const float* __restrict__ wk,
    const float* __restrict__ wv, unsigned short* __restrict__ wbf)
{
    const int col = blockIdx.x;            // 0..191
    const int p = col >> 6, h = col & 63;
    const float* src = (p == 0 ? wq : (p == 1 ? wk : wv)) + (size_t)h * D_;
    const int t = threadIdx.x;
    const float4 v = ((const float4*)src)[t];
    ushort4 o;
    o.x = f2bf(v.x); o.y = f2bf(v.y); o.z = f2bf(v.z); o.w = f2bf(v.w);
    *(ushort4*)&wbf[(size_t)col * D_ + 4 * t] = o;
}

// ------------------------------------------------------------------
// Kernel 1: QKV projection via bf16 MFMA (16x16x32).
// grid = (256, 2): blockIdx.y picks a 96-col half (6 col-tiles) so two
// blocks/CU overlap latency. Wave w owns rows 16w..16w+15.
// Fragment layouts (validated by this kernel passing in R3):
//   A: lane elem j = A[m = lane&15][k = (lane>>4)*8 + j]
//   B: lane elem j = B[k = (lane>>4)*8 + j][n = lane&15]  (reads src row-major)
//   C/D: reg r -> row = (lane>>4)*4 + r, col = lane&15
// ------------------------------------------------------------------
__global__ __launch_bounds__(256) void proj_mfma(
    const float* __restrict__ x, const unsigned short* __restrict__ wbf,
    const float* __restrict__ bq, const float* __restrict__ bk,
    const float* __restrict__ bv,
    float* __restrict__ qo, float* __restrict__ ko, float* __restrict__ vo)
{
    __shared__ unsigned short xbf[64][72];    // 9216 B
    __shared__ unsigned short wsh[96][72];    // 13824 B

    const int t = threadIdx.x;
    const int wid = t >> 6, lane = t & 63;
    const size_t row0 = (size_t)blockIdx.x * 64;
    const int colbase = 96 * blockIdx.y;

    f32x4 acc[6];
#pragma unroll
    for (int i = 0; i < 6; ++i) acc[i] = (f32x4)0.f;

    const int arow = 16 * wid + (lane & 15);
    const int koff = (lane >> 4) * 8;

    for (int chunk = 0; chunk < 16; ++chunk) {
        const int d0 = chunk * 64;
        __syncthreads();
        // stage x: 64 rows x 64 d, fp32 -> bf16
#pragma unroll
        for (int i = 0; i < 4; ++i) {
            int e = t + i * 256;              // 0..1023 float4
            int r = e >> 4, c4 = (e & 15) * 4;
            float4 v = *(const float4*)&x[(row0 + r) * D_ + d0 + c4];
            ushort4 o;
            o.x = f2bf(v.x); o.y = f2bf(v.y); o.z = f2bf(v.z); o.w = f2bf(v.w);
            *(ushort4*)&xbf[r][c4] = o;
        }
        // stage w: 96 cols x 64 d bf16
#pragma unroll
        for (int i = 0; i < 3; ++i) {
            int e = t + i * 256;              // 0..767
            int col = e >> 3, g = e & 7;
            uint4 v = *(const uint4*)&wbf[(size_t)(colbase + col) * D_ + d0 + 8 * g];
            *(uint4*)&wsh[col][8 * g] = v;
        }
        __syncthreads();

#pragma unroll
        for (int ks2 = 0; ks2 < 2; ++ks2) {
            const int k0 = ks2 * 32;
            const bf16x8 a = *(const bf16x8*)&xbf[arow][k0 + koff];
#pragma unroll
            for (int ct = 0; ct < 6; ++ct) {
                const bf16x8 b = *(const bf16x8*)&wsh[16 * ct + (lane & 15)][k0 + koff];
                acc[ct] = __builtin_amdgcn_mfma_f32_16x16x32_bf16(a, b, acc[ct], 0, 0, 0);
            }
        }
    }

    // epilogue: add bias, scatter to q/k/v
#pragma unroll
    for (int ct = 0; ct < 6; ++ct) {
        const int gct = 6 * blockIdx.y + ct;
        const int p = gct >> 2, h0 = (gct & 3) * 16;
        const float* bias = (p == 0 ? bq : (p == 1 ? bk : bv));
        float* out = (p == 0 ? qo : (p == 1 ? ko : vo));
        const float bb = bias[h0 + (lane & 15)];
#pragma unroll
        for (int r = 0; r < 4; ++r) {
            const int row = 16 * wid + (lane >> 4) * 4 + r;
            out[(row0 + row) * HD_ + h0 + (lane & 15)] = acc[ct][r] + bb;
        }
    }
}

// ------------------------------------------------------------------
// Kernel 2: split-K causal flash attention, bf16 MFMA.
// Block = 4 waves; wave w owns q-rows 16w..16w+15 of the 64-q tile.
// Per k-tile (64 keys):
//   S^T = K·Q^T  (A = K rows, B = Q rows; C: row=key, col=q)
//   softmax per column q (in-lane reduce + shfl_xor 16/32)
//   P^T packed (4 consecutive keys/reg) -> per-wave LDS p[q][key] bf16
//   O += P·V     (A = p rows, B = vT rows; C: row=q, col=h)
// alpha/l per-column -> per-row via __shfl.
// ------------------------------------------------------------------
__global__ __launch_bounds__(256) void flash_splitk(
    const float* __restrict__ qg, const float* __restrict__ kg,
    const float* __restrict__ vg, float* __restrict__ out,
    float* __restrict__ part)
{
    __shared__ unsigned short qbf[64][72];      // 9216 B  Q rows (pre-scaled)
    __shared__ unsigned short kbf[64][72];      // 9216 B  K rows
    __shared__ unsigned short vT [64][72];      // 9216 B  vT[h][key]
    __shared__ unsigned short psh[4][16][72];   // 9216 B  per-wave P[q][key]

    const int t    = threadIdx.x;
    const int w    = t >> 6;
    const int lane = t & 63;
    const int n    = lane & 15;      // MFMA col index
    const int g    = lane >> 4;      // MFMA row group
    const int koff = 8 * g;
    const int b    = blockIdx.y;

    // decode blockIdx.x -> (qi, c)
    int qi = 0, rem = blockIdx.x;
    while (rem >= ((qi >> 3) + 1)) { rem -= (qi >> 3) + 1; ++qi; }
    const int c   = rem;
    const int kt0 = c * CK;
    const int kt1 = min(qi, kt0 + CK - 1);
    const int nc  = (qi >> 3) + 1;

    const size_t qbase = ((size_t)b * S_ + (size_t)qi * 64) * HD_;

    // stage Q (once), pre-scaled by 1/sqrt(64) = 0.125 (exact pow2)
#pragma unroll
    for (int i = 0; i < 4; ++i) {
        int e = t + i * 256;
        int r = e >> 4, c4 = (e & 15) * 4;
        float4 v = *(const float4*)&qg[qbase + (size_t)r * HD_ + c4];
        ushort4 o;
        o.x = f2bf(v.x * 0.125f); o.y = f2bf(v.y * 0.125f);
        o.z = f2bf(v.z * 0.125f); o.w = f2bf(v.w * 0.125f);
        *(ushort4*)&qbf[r][c4] = o;
    }

    f32x4 o4[4];
#pragma unroll
    for (int i = 0; i < 4; ++i) o4[i] = (f32x4)0.f;
    float m_r = -INFINITY, l_r = 0.f;

    for (int kt = kt0; kt <= kt1; ++kt) {
        const size_t kvbase = ((size_t)b * S_ + (size_t)kt * 64) * HD_;
        __syncthreads();                         // prev reads done (also covers qbf on iter 0)
        // stage K row-major bf16
#pragma unroll
        for (int i = 0; i < 4; ++i) {
            int e = t + i * 256;
            int r = e >> 4, c4 = (e & 15) * 4;
            float4 v = *(const float4*)&kg[kvbase + (size_t)r * HD_ + c4];
            ushort4 o;
            o.x = f2bf(v.x); o.y = f2bf(v.y); o.z = f2bf(v.z); o.w = f2bf(v.w);
            *(ushort4*)&kbf[r][c4] = o;
        }
        // stage V transposed: thread (h = t&63, key block = 16*(t>>6))
        {
            const int h = t & 63, kb16 = 16 * (t >> 6);
#pragma unroll
            for (int j = 0; j < 4; ++j) {
                float v0 = vg[kvbase + (size_t)(kb16 + 4 * j + 0) * HD_ + h];
                float v1 = vg[kvbase + (size_t)(kb16 + 4 * j + 1) * HD_ + h];
                float v2 = vg[kvbase + (size_t)(kb16 + 4 * j + 2) * HD_ + h];
                float v3 = vg[kvbase + (size_t)(kb16 + 4 * j + 3) * HD_ + h];
                ushort4 o;
                o.x = f2bf(v0); o.y = f2bf(v1); o.z = f2bf(v2); o.w = f2bf(v3);
                *(ushort4*)&vT[h][kb16 + 4 * j] = o;
            }
        }
        __syncthreads();

        // ---- S^T = K . Q^T : 4 m-tiles (keys) x 16 q ----
        f32x4 sc[4];
#pragma unroll
        for (int mt = 0; mt < 4; ++mt) sc[mt] = (f32x4)0.f;
#pragma unroll
        for (int ks = 0; ks < 2; ++ks) {
            const bf16x8 bq8 = *(const bf16x8*)&qbf[16 * w + n][32 * ks + koff];
#pragma unroll
            for (int mt = 0; mt < 4; ++mt) {
                const bf16x8 ak = *(const bf16x8*)&kbf[16 * mt + n][32 * ks + koff];
                sc[mt] = __builtin_amdgcn_mfma_f32_16x16x32_bf16(ak, bq8, sc[mt], 0, 0, 0);
            }
        }

        // ---- causal mask (diagonal k-tile only; kt==qi) ----
        if (kt == qi) {
            const int qloc = 16 * w + n;         // this column's q within tile
#pragma unroll
            for (int mt = 0; mt < 4; ++mt)
#pragma unroll
                for (int r = 0; r < 4; ++r) {
                    const int kloc = 16 * mt + 4 * g + r;
                    if (kloc > qloc) sc[mt][r] = -INFINITY;
                }
        }

        // ---- online softmax per column q ----
        float mx = -INFINITY;
#pragma unroll
        for (int mt = 0; mt < 4; ++mt)
#pragma unroll
            for (int r = 0; r < 4; ++r) mx = fmaxf(mx, sc[mt][r]);
        mx = fmaxf(mx, __shfl_xor(mx, 16));
        mx = fmaxf(mx, __shfl_xor(mx, 32));

        const float m_new = fmaxf(m_r, mx);
        const float alpha = __expf(m_r - m_new);
        float psum = 0.f;
#pragma unroll
        for (int mt = 0; mt < 4; ++mt)
#pragma unroll
            for (int r = 0; r < 4; ++r) {
                const float p = __expf(sc[mt][r] - m_new);
                sc[mt][r] = p;
                psum += p;
            }
        psum += __shfl_xor(psum, 16);
        psum += __shfl_xor(psum, 32);
        l_r = l_r * alpha + psum;
        m_r = m_new;

        // rescale O rows (row q = 4g+r needs alpha of column 4g+r)
#pragma unroll
        for (int r = 0; r < 4; ++r) {
            const float ar = __shfl(alpha, 4 * g + r);
#pragma unroll
            for (int ht = 0; ht < 4; ++ht) o4[ht][r] *= ar;
        }

        // ---- pack P^T -> per-wave LDS p[q][key] (4 consecutive keys/reg) ----
#pragma unroll
        for (int mt = 0; mt < 4; ++mt) {
            ushort4 u;
            u.x = f2bf(sc[mt][0]); u.y = f2bf(sc[mt][1]);
            u.z = f2bf(sc[mt][2]); u.w = f2bf(sc[mt][3]);
            *(ushort4*)&psh[w][n][16 * mt + 4 * g] = u;
        }
        // same-wave RAW on LDS: compiler inserts lgkmcnt wait; no barrier needed

        // ---- O += P . V ----
#pragma unroll
        for (int ks = 0; ks < 2; ++ks) {
            const bf16x8 ap = *(const bf16x8*)&psh[w][n][32 * ks + koff];
#pragma unroll
            for (int ht = 0; ht < 4; ++ht) {
                const bf16x8 bv8 = *(const bf16x8*)&vT[16 * ht + n][32 * ks + koff];
                o4[ht] = __builtin_amdgcn_mfma_f32_16x16x32_bf16(ap, bv8, o4[ht], 0, 0, 0);
            }
        }
    }

    if (nc == 1) {
#pragma unroll
        for (int r = 0; r < 4; ++r) {
            const float lr = __shfl(l_r, 4 * g + r);
            const float inv = 1.f / lr;
            const size_t ob = qbase + (size_t)(16 * w + 4 * g + r) * HD_;
#pragma unroll
            for (int ht = 0; ht < 4; ++ht)
                out[ob + 16 * ht + n] = o4[ht][r] * inv;
        }
    } else {
        const size_t sb = ((size_t)b * CHUNKS_PER_B + blockIdx.x) * SLOT_F;
#pragma unroll
        for (int r = 0; r < 4; ++r) {
            const size_t pb = sb + (size_t)(16 * w + 4 * g + r) * PSTRIDE;
#pragma unroll
            for (int ht = 0; ht < 4; ++ht)
                part[pb + 16 * ht + n] = o4[ht][r];
        }
        if (g == 0) {
            part[sb + (size_t)(16 * w + n) * PSTRIDE + 64] = m_r;
            part[sb + (size_t)(16 * w + n) * PSTRIDE + 65] = l_r;
        }
    }
}

// ------------------------------------------------------------------
// Kernel 3: merge partials for qi >= CK.  grid = (56, B).
// ------------------------------------------------------------------
__global__ __launch_bounds__(256) void combine(
    const float* __restrict__ part, float* __restrict__ out)
{
    const int t  = threadIdx.x;
    const int qr = t >> 2, tc = t & 3;
    const int qi = blockIdx.x + CK;          // 8..63
    const int b  = blockIdx.y;
    const int nc = (qi >> 3) + 1;

    int cum = 0;
    for (int j = 0; j < qi; ++j) cum += (j >> 3) + 1;
    const size_t base0 = ((size_t)b * CHUNKS_PER_B + cum) * SLOT_F;

    float M = -INFINITY;
    for (int c0 = 0; c0 < nc; ++c0)
        M = fmaxf(M, part[base0 + (size_t)c0 * SLOT_F + qr * PSTRIDE + 64]);

    float L = 0.f;
    float o[16];
#pragma unroll
    for (int j = 0; j < 16; ++j) o[j] = 0.f;

    for (int c0 = 0; c0 < nc; ++c0) {
        const size_t sb = base0 + (size_t)c0 * SLOT_F + qr * PSTRIDE;
        const float m_c = part[sb + 64];
        const float l_c = part[sb + 65];
        const float w = __expf(m_c - M);
        L += w * l_c;
#pragma unroll
        for (int j = 0; j < 4; ++j) {
            const float4 ov = *(const float4*)&part[sb + tc * 16 + 4 * j];
            o[4 * j + 0] += w * ov.x; o[4 * j + 1] += w * ov.y;
            o[4 * j + 2] += w * ov.z; o[4 * j + 3] += w * ov.w;
        }
    }

    const float inv = 1.f / L;
    const size_t qbase = ((size_t)b * S_ + (size_t)qi * 64) * HD_;
#pragma unroll
    for (int j = 0; j < 4; ++j) {
        float4 r;
        r.x = o[4 * j + 0] * inv; r.y = o[4 * j + 1] * inv;
        r.z = o[4 * j + 2] * inv; r.w = o[4 * j + 3] * inv;
        *(float4*)&out[qbase + 16 * t + 4 * j] = r;
    }
}

// ------------------------------------------------------------------
extern "C" void kernel_launch(void* const* d_in, const int* in_sizes, int n_in,
                              void* d_out, int out_size, void* d_ws, size_t ws_size,
                              hipStream_t stream)
{
    const float* x  = (const float*)d_in[0];
    const float* wq = (const float*)d_in[1];
    const float* bq = (const float*)d_in[2];
    const float* wk = (const float*)d_in[3];
    const float* bk = (const float*)d_in[4];
    const float* wv = (const float*)d_in[5];
    const float* bv = (const float*)d_in[6];
    float* outp = (float*)d_out;

    // ws layout (floats): q | k | v | wbf(bf16) | partials
    const size_t n = (size_t)B_ * S_ * HD_;        // 1048576
    float* qb = (float*)d_ws;
    float* kb = qb + n;
    float* vb = kb + n;
    unsigned short* wbf = (unsigned short*)(vb + n);          // 192*1024 bf16
    float* part = (float*)(wbf + (size_t)192 * D_);           // 4*288*4352 floats

    convert_w<<<dim3(192), 256, 0, stream>>>(wq, wk, wv, wbf);
    proj_mfma<<<dim3(B_ * S_ / 64, 2), 256, 0, stream>>>(
        x, wbf, bq, bk, bv, qb, kb, vb);
    flash_splitk<<<dim3(CHUNKS_PER_B, B_), 256, 0, stream>>>(qb, kb, vb, outp, part);
    combine<<<dim3(S_ / 64 - CK, B_), 256, 0, stream>>>(part, outp);
}

// Round 5
// 174.015 us; speedup vs baseline: 4.9260x; 1.1188x over previous
//
#include <hip/hip_runtime.h>
#include <math.h>

#define B_   4
#define S_   4096
#define D_   1024
#define HD_  64

// ---------------- split-K flash constants ----------------
#define CK            8          // k-tiles (of 64 keys) per chunk
#define CHUNKS_PER_B  288        // sum_{qi=0}^{63} (qi/8 + 1)
#define PSTRIDE       68         // floats per row in a partial slot (o[64], m, l, pad)
#define SLOT_F        (64 * PSTRIDE)

typedef float  f32x4  __attribute__((ext_vector_type(4)));
typedef __bf16 bf16x8 __attribute__((ext_vector_type(8)));

static __device__ __forceinline__ unsigned short f2bf(float f) {
    unsigned int u = __float_as_uint(f);
    u += 0x7FFFu + ((u >> 16) & 1u);          // round-to-nearest-even
    return (unsigned short)(u >> 16);
}

// ------------------------------------------------------------------
// Kernel 0: convert wq/wk/wv (fp32 [64][1024]) into wbf (bf16 [192][1024]).
// ------------------------------------------------------------------
__global__ __launch_bounds__(256) void convert_w(
    const float* __restrict__ wq, const float* __restrict__ wk,
    const float* __restrict__ wv, unsigned short* __restrict__ wbf)
{
    const int col = blockIdx.x;            // 0..191
    const int p = col >> 6, h = col & 63;
    const float* src = (p == 0 ? wq : (p == 1 ? wk : wv)) + (size_t)h * D_;
    const int t = threadIdx.x;
    const float4 v = ((const float4*)src)[t];
    ushort4 o;
    o.x = f2bf(v.x); o.y = f2bf(v.y); o.z = f2bf(v.z); o.w = f2bf(v.w);
    *(ushort4*)&wbf[(size_t)col * D_ + 4 * t] = o;
}

// ------------------------------------------------------------------
// Kernel 1: QKV projection via bf16 MFMA (16x16x32).
// grid = (512, 2): 32 rows x 96 cols per block -> 1024 blocks = 4/CU
// (16 waves/CU; LDS 18.4 KB). Wave w: row-tile rt = w&1, col-group
// cg = w>>1 (3 col-tiles each).
// Outputs bf16 directly: qbf (pre-scaled by 0.125), kbf row-major
// [B*S][64]; v transposed vt[b][h][s] (8B packed stores along s).
// Fragment layouts (validated in R3/R4):
//   A: lane elem j = A[m = lane&15][k = (lane>>4)*8 + j]
//   B: lane elem j = B[k = (lane>>4)*8 + j][n = lane&15]
//   C/D: reg r -> row = (lane>>4)*4 + r, col = lane&15
// ------------------------------------------------------------------
__global__ __launch_bounds__(256) void proj_mfma(
    const float* __restrict__ x, const unsigned short* __restrict__ wbf,
    const float* __restrict__ bq, const float* __restrict__ bk,
    const float* __restrict__ bv,
    unsigned short* __restrict__ qbf, unsigned short* __restrict__ kbf,
    unsigned short* __restrict__ vtb)
{
    __shared__ unsigned short xs[32][72];     // 4608 B
    __shared__ unsigned short wsh[96][72];    // 13824 B

    const int t = threadIdx.x;
    const int w = t >> 6, lane = t & 63;
    const int n = lane & 15, g = lane >> 4;
    const int koff = 8 * g;
    const int rt = w & 1, cg = w >> 1;
    const size_t row0 = (size_t)blockIdx.x * 32;
    const int colbase = 96 * blockIdx.y;

    f32x4 acc[3];
#pragma unroll
    for (int i = 0; i < 3; ++i) acc[i] = (f32x4)0.f;

    for (int chunk = 0; chunk < 16; ++chunk) {
        const int d0 = chunk * 64;
        __syncthreads();
        // stage x: 32 rows x 64 d, fp32 -> bf16 (2 float4/thread)
#pragma unroll
        for (int i = 0; i < 2; ++i) {
            int e = t + i * 256;              // 0..511 float4
            int r = e >> 4, c4 = (e & 15) * 4;
            float4 v = *(const float4*)&x[(row0 + r) * D_ + d0 + c4];
            ushort4 o;
            o.x = f2bf(v.x); o.y = f2bf(v.y); o.z = f2bf(v.z); o.w = f2bf(v.w);
            *(ushort4*)&xs[r][c4] = o;
        }
        // stage w: 96 cols x 64 d bf16 (3 uint4/thread)
#pragma unroll
        for (int i = 0; i < 3; ++i) {
            int e = t + i * 256;              // 0..767
            int col = e >> 3, gg = e & 7;
            uint4 v = *(const uint4*)&wbf[(size_t)(colbase + col) * D_ + d0 + 8 * gg];
            *(uint4*)&wsh[col][8 * gg] = v;
        }
        __syncthreads();

#pragma unroll
        for (int ks = 0; ks < 2; ++ks) {
            const int k0 = 32 * ks;
            const bf16x8 a = *(const bf16x8*)&xs[16 * rt + n][k0 + koff];
#pragma unroll
            for (int ci = 0; ci < 3; ++ci) {
                const bf16x8 b = *(const bf16x8*)&wsh[48 * cg + 16 * ci + n][k0 + koff];
                acc[ci] = __builtin_amdgcn_mfma_f32_16x16x32_bf16(a, b, acc[ci], 0, 0, 0);
            }
        }
    }

    // epilogue
#pragma unroll
    for (int ci = 0; ci < 3; ++ci) {
        const int gct = 6 * blockIdx.y + 3 * cg + ci;
        const int p = gct >> 2, h0 = (gct & 3) * 16;
        const int h = h0 + n;
        const float bb = (p == 0 ? bq : (p == 1 ? bk : bv))[h];
        if (p == 2) {
            // v transposed: vt[b][h][s], 4 consecutive s packed
            const size_t grow0 = row0 + 16 * rt + 4 * g;
            const int bidx = (int)(grow0 >> 12);
            const int s0 = (int)(grow0 & 4095);
            ushort4 u;
            u.x = f2bf(acc[ci][0] + bb); u.y = f2bf(acc[ci][1] + bb);
            u.z = f2bf(acc[ci][2] + bb); u.w = f2bf(acc[ci][3] + bb);
            *(ushort4*)&vtb[((size_t)bidx * HD_ + h) * S_ + s0] = u;
        } else {
            unsigned short* outp = (p == 0 ? qbf : kbf);
            const float scale = (p == 0) ? 0.125f : 1.0f;
#pragma unroll
            for (int r = 0; r < 4; ++r) {
                const size_t grow = row0 + 16 * rt + 4 * g + r;
                outp[grow * HD_ + h] = f2bf((acc[ci][r] + bb) * scale);
            }
        }
    }
}

// ------------------------------------------------------------------
// Kernel 2: split-K causal flash attention, bf16 MFMA, bf16 inputs.
// Same structure as R4 (verified): wave w owns q-rows 16w..16w+15.
//   S^T = K·Q^T ; per-column online softmax; P^T packed to per-wave
//   LDS; O += P·V with vT B-fragments. Staging is now pure uint4
//   copies (no fp32->bf16 conversion).
// ------------------------------------------------------------------
__global__ __launch_bounds__(256) void flash_splitk(
    const unsigned short* __restrict__ qg, const unsigned short* __restrict__ kg,
    const unsigned short* __restrict__ vt, float* __restrict__ out,
    float* __restrict__ part)
{
    __shared__ unsigned short qsh[64][72];      // 9216 B  Q rows (pre-scaled)
    __shared__ unsigned short ksh[64][72];      // 9216 B  K rows
    __shared__ unsigned short vsh[64][72];      // 9216 B  vT[h][key]
    __shared__ unsigned short psh[4][16][72];   // 9216 B  per-wave P[q][key]

    const int t    = threadIdx.x;
    const int w    = t >> 6;
    const int lane = t & 63;
    const int n    = lane & 15;      // MFMA col index
    const int g    = lane >> 4;      // MFMA row group
    const int koff = 8 * g;
    const int b    = blockIdx.y;

    // decode blockIdx.x -> (qi, c)
    int qi = 0, rem = blockIdx.x;
    while (rem >= ((qi >> 3) + 1)) { rem -= (qi >> 3) + 1; ++qi; }
    const int c   = rem;
    const int kt0 = c * CK;
    const int kt1 = min(qi, kt0 + CK - 1);
    const int nc  = (qi >> 3) + 1;

    const size_t qtile = ((size_t)b * S_ + (size_t)qi * 64) * HD_;

    // stage Q (once): 2 uint4/thread
    {
        const uint4* src = (const uint4*)(qg + qtile);
#pragma unroll
        for (int i = 0; i < 2; ++i) {
            int e = t + i * 256;                // 0..511
            int r = e >> 3, gg = e & 7;
            *(uint4*)&qsh[r][8 * gg] = src[e];
        }
    }

    f32x4 o4[4];
#pragma unroll
    for (int i = 0; i < 4; ++i) o4[i] = (f32x4)0.f;
    float m_r = -INFINITY, l_r = 0.f;

    for (int kt = kt0; kt <= kt1; ++kt) {
        const size_t kvbase = ((size_t)b * S_ + (size_t)kt * 64) * HD_;
        __syncthreads();                        // prev reads done (covers qsh on iter 0)
        {
            const uint4* ksrc = (const uint4*)(kg + kvbase);
#pragma unroll
            for (int i = 0; i < 2; ++i) {
                int e = t + i * 256;
                int r = e >> 3, gg = e & 7;
                *(uint4*)&ksh[r][8 * gg] = ksrc[e];
            }
#pragma unroll
            for (int i = 0; i < 2; ++i) {
                int e = t + i * 256;
                int h = e >> 3, gg = e & 7;     // vt[b][h][kt*64 + 8gg..]
                *(uint4*)&vsh[h][8 * gg] =
                    *(const uint4*)&vt[((size_t)b * HD_ + h) * S_ + kt * 64 + 8 * gg];
            }
        }
        __syncthreads();

        // ---- S^T = K . Q^T : 4 m-tiles (keys) x 16 q ----
        f32x4 sc[4];
#pragma unroll
        for (int mt = 0; mt < 4; ++mt) sc[mt] = (f32x4)0.f;
#pragma unroll
        for (int ks = 0; ks < 2; ++ks) {
            const bf16x8 bq8 = *(const bf16x8*)&qsh[16 * w + n][32 * ks + koff];
#pragma unroll
            for (int mt = 0; mt < 4; ++mt) {
                const bf16x8 ak = *(const bf16x8*)&ksh[16 * mt + n][32 * ks + koff];
                sc[mt] = __builtin_amdgcn_mfma_f32_16x16x32_bf16(ak, bq8, sc[mt], 0, 0, 0);
            }
        }

        // ---- causal mask (diagonal k-tile only) ----
        if (kt == qi) {
            const int qloc = 16 * w + n;
#pragma unroll
            for (int mt = 0; mt < 4; ++mt)
#pragma unroll
                for (int r = 0; r < 4; ++r) {
                    const int kloc = 16 * mt + 4 * g + r;
                    if (kloc > qloc) sc[mt][r] = -INFINITY;
                }
        }

        // ---- online softmax per column q ----
        float mx = -INFINITY;
#pragma unroll
        for (int mt = 0; mt < 4; ++mt)
#pragma unroll
            for (int r = 0; r < 4; ++r) mx = fmaxf(mx, sc[mt][r]);
        mx = fmaxf(mx, __shfl_xor(mx, 16));
        mx = fmaxf(mx, __shfl_xor(mx, 32));

        const float m_new = fmaxf(m_r, mx);
        const float alpha = __expf(m_r - m_new);
        float psum = 0.f;
#pragma unroll
        for (int mt = 0; mt < 4; ++mt)
#pragma unroll
            for (int r = 0; r < 4; ++r) {
                const float p = __expf(sc[mt][r] - m_new);
                sc[mt][r] = p;
                psum += p;
            }
        psum += __shfl_xor(psum, 16);
        psum += __shfl_xor(psum, 32);
        l_r = l_r * alpha + psum;
        m_r = m_new;

        // rescale O rows (row q = 4g+r needs alpha of column 4g+r)
#pragma unroll
        for (int r = 0; r < 4; ++r) {
            const float ar = __shfl(alpha, 4 * g + r);
#pragma unroll
            for (int ht = 0; ht < 4; ++ht) o4[ht][r] *= ar;
        }

        // ---- pack P^T -> per-wave LDS p[q][key] ----
#pragma unroll
        for (int mt = 0; mt < 4; ++mt) {
            ushort4 u;
            u.x = f2bf(sc[mt][0]); u.y = f2bf(sc[mt][1]);
            u.z = f2bf(sc[mt][2]); u.w = f2bf(sc[mt][3]);
            *(ushort4*)&psh[w][n][16 * mt + 4 * g] = u;
        }
        // same-wave RAW on LDS: compiler inserts lgkmcnt wait; no barrier needed

        // ---- O += P . V ----
#pragma unroll
        for (int ks = 0; ks < 2; ++ks) {
            const bf16x8 ap = *(const bf16x8*)&psh[w][n][32 * ks + koff];
#pragma unroll
            for (int ht = 0; ht < 4; ++ht) {
                const bf16x8 bv8 = *(const bf16x8*)&vsh[16 * ht + n][32 * ks + koff];
                o4[ht] = __builtin_amdgcn_mfma_f32_16x16x32_bf16(ap, bv8, o4[ht], 0, 0, 0);
            }
        }
    }

    const size_t qbase = ((size_t)b * S_ + (size_t)qi * 64) * HD_;
    if (nc == 1) {
#pragma unroll
        for (int r = 0; r < 4; ++r) {
            const float lr = __shfl(l_r, 4 * g + r);
            const float inv = 1.f / lr;
            const size_t ob = qbase + (size_t)(16 * w + 4 * g + r) * HD_;
#pragma unroll
            for (int ht = 0; ht < 4; ++ht)
                out[ob + 16 * ht + n] = o4[ht][r] * inv;
        }
    } else {
        const size_t sb = ((size_t)b * CHUNKS_PER_B + blockIdx.x) * SLOT_F;
#pragma unroll
        for (int r = 0; r < 4; ++r) {
            const size_t pb = sb + (size_t)(16 * w + 4 * g + r) * PSTRIDE;
#pragma unroll
            for (int ht = 0; ht < 4; ++ht)
                part[pb + 16 * ht + n] = o4[ht][r];
        }
        if (g == 0) {
            part[sb + (size_t)(16 * w + n) * PSTRIDE + 64] = m_r;
            part[sb + (size_t)(16 * w + n) * PSTRIDE + 65] = l_r;
        }
    }
}

// ------------------------------------------------------------------
// Kernel 3: merge partials for qi >= CK.  grid = (56, B).
// ------------------------------------------------------------------
__global__ __launch_bounds__(256) void combine(
    const float* __restrict__ part, float* __restrict__ out)
{
    const int t  = threadIdx.x;
    const int qr = t >> 2, tc = t & 3;
    const int qi = blockIdx.x + CK;          // 8..63
    const int b  = blockIdx.y;
    const int nc = (qi >> 3) + 1;

    int cum = 0;
    for (int j = 0; j < qi; ++j) cum += (j >> 3) + 1;
    const size_t base0 = ((size_t)b * CHUNKS_PER_B + cum) * SLOT_F;

    float M = -INFINITY;
    for (int c0 = 0; c0 < nc; ++c0)
        M = fmaxf(M, part[base0 + (size_t)c0 * SLOT_F + qr * PSTRIDE + 64]);

    float L = 0.f;
    float o[16];
#pragma unroll
    for (int j = 0; j < 16; ++j) o[j] = 0.f;

    for (int c0 = 0; c0 < nc; ++c0) {
        const size_t sb = base0 + (size_t)c0 * SLOT_F + qr * PSTRIDE;
        const float m_c = part[sb + 64];
        const float l_c = part[sb + 65];
        const float w = __expf(m_c - M);
        L += w * l_c;
#pragma unroll
        for (int j = 0; j < 4; ++j) {
            const float4 ov = *(const float4*)&part[sb + tc * 16 + 4 * j];
            o[4 * j + 0] += w * ov.x; o[4 * j + 1] += w * ov.y;
            o[4 * j + 2] += w * ov.z; o[4 * j + 3] += w * ov.w;
        }
    }

    const float inv = 1.f / L;
    const size_t qbase = ((size_t)b * S_ + (size_t)qi * 64) * HD_;
#pragma unroll
    for (int j = 0; j < 4; ++j) {
        float4 r;
        r.x = o[4 * j + 0] * inv; r.y = o[4 * j + 1] * inv;
        r.z = o[4 * j + 2] * inv; r.w = o[4 * j + 3] * inv;
        *(float4*)&out[qbase + 16 * t + 4 * j] = r;
    }
}

// ------------------------------------------------------------------
extern "C" void kernel_launch(void* const* d_in, const int* in_sizes, int n_in,
                              void* d_out, int out_size, void* d_ws, size_t ws_size,
                              hipStream_t stream)
{
    const float* x  = (const float*)d_in[0];
    const float* wq = (const float*)d_in[1];
    const float* bq = (const float*)d_in[2];
    const float* wk = (const float*)d_in[3];
    const float* bk = (const float*)d_in[4];
    const float* wv = (const float*)d_in[5];
    const float* bv = (const float*)d_in[6];
    float* outp = (float*)d_out;

    // ws layout: qbf | kbf | vt (bf16, n each) | wbf (bf16) | part (fp32)
    const size_t n = (size_t)B_ * S_ * HD_;        // 1048576
    unsigned short* qbf = (unsigned short*)d_ws;
    unsigned short* kbf = qbf + n;
    unsigned short* vtb = kbf + n;
    unsigned short* wbf = vtb + n;                 // 192*1024 bf16
    float* part = (float*)(wbf + (size_t)192 * D_);

    convert_w<<<dim3(192), 256, 0, stream>>>(wq, wk, wv, wbf);
    proj_mfma<<<dim3(B_ * S_ / 32, 2), 256, 0, stream>>>(
        x, wbf, bq, bk, bv, qbf, kbf, vtb);
    flash_splitk<<<dim3(CHUNKS_PER_B, B_), 256, 0, stream>>>(qbf, kbf, vtb, outp, part);
    combine<<<dim3(S_ / 64 - CK, B_), 256, 0, stream>>>(part, outp);
}